// Round 3
// baseline (497.211 us; speedup 1.0000x reference)
//
#include <hip/hip_runtime.h>

#define NN 80
#define NP4 1600            // float4 elements per 80x80 tile
#define NPAIR 6400
#define MAXIT 60
#define TOLV 1e-3f
#define GRID 768            // 3 blocks per CU (LDS-limited)
#define NCHUNK 7            // ceil(1600 float4 / 256 threads)

// Row dot-product: A-row and v read as float4 from LDS, chunk order rotated by
// q0 per thread so lanes hit distinct bank groups (stride-80 rows would
// otherwise be a 32-way conflict).
__device__ __forceinline__ float matvec_row(const float4* __restrict__ Ar4,
                                            const float4* __restrict__ v4,
                                            int q0) {
    float s0 = 0.f, s1 = 0.f, s2 = 0.f, s3 = 0.f;
    int q = q0;
#pragma unroll
    for (int c = 0; c < 20; ++c) {
        const float4 a = Ar4[q];
        const float4 w = v4[q];
        s0 = fmaf(a.x, w.x, s0);
        s1 = fmaf(a.y, w.y, s1);
        s2 = fmaf(a.z, w.z, s2);
        s3 = fmaf(a.w, w.w, s3);
        q = (q == 19) ? 0 : q + 1;
    }
    return (s0 + s1) + (s2 + s3);
}

__global__ __launch_bounds__(256, 3) void pair_kernel(
    const float* __restrict__ r_zeros,
    const float* __restrict__ r_const,
    const float* __restrict__ t_paths,
    const float* __restrict__ weights_t,
    const float* __restrict__ weights_r,
    float* __restrict__ out)
{
    __shared__ float A[2][NN * NN];   // 2 x 25.6 KB, linear (no pad)
    __shared__ float v[NN];
    __shared__ float red1[4], red2[4];

    const int tid  = threadIdx.x;
    const int lane = tid & 63;
    const int wid  = tid >> 6;
    const int q0   = (tid < NN) ? (tid % 20) : 0;

    // ---- combine first pair directly into A[0] ----
    {
        const float4* wr4 = (const float4*)weights_r + (long)blockIdx.x * NP4;
        const float4* rz4 = (const float4*)r_zeros  + (long)blockIdx.x * NP4;
        const float4* rc4 = (const float4*)r_const  + (long)blockIdx.x * NP4;
        for (int i4 = tid; i4 < NP4; i4 += 256) {
            float4 a = wr4[i4], b = rz4[i4], d = rc4[i4];
            float4 o;
            o.x = fmaf(a.x, b.x, d.x);
            o.y = fmaf(a.y, b.y, d.y);
            o.z = fmaf(a.z, b.z, d.z);
            o.w = fmaf(a.w, b.w, d.w);
            *(float4*)&A[0][i4 * 4] = o;
        }
    }

    int cur = 0;
    for (int p = blockIdx.x; p < NPAIR; p += GRID) {
        const int  np = p + GRID;
        const bool hn = np < NPAIR;
        const float4* nwr = (const float4*)weights_r + (long)np * NP4;
        const float4* nrz = (const float4*)r_zeros  + (long)np * NP4;
        const float4* nrc = (const float4*)r_const  + (long)np * NP4;
        float* nd = A[cur ^ 1];
        int k = 0;
        // one prefetch-combine chunk of the NEXT pair (all 256 threads)
        auto pf = [&]() {
            if (hn && k < NCHUNK) {
                const int i4 = k * 256 + tid;
                if (i4 < NP4) {
                    float4 a = nwr[i4], b = nrz[i4], d = nrc[i4];
                    float4 o;
                    o.x = fmaf(a.x, b.x, d.x);
                    o.y = fmaf(a.y, b.y, d.y);
                    o.z = fmaf(a.z, b.z, d.z);
                    o.w = fmaf(a.w, b.w, d.w);
                    *(float4*)&nd[i4 * 4] = o;
                }
                ++k;
            }
        };

        const float4* Ar4 = (const float4*)&A[cur][tid * NN];
        const float4* v4  = (const float4*)v;

        if (tid < NN) v[tid] = 0.11180339887498949f;   // 1/sqrt(80)
        __syncthreads();

        // ---- prologue: Av0, ev0, ||Av0||^2 (merged float2 reduce) ----
        float Avp = (tid < NN) ? matvec_row(Ar4, v4, q0) : 0.f;
        float q1  = (tid < NN) ? v[tid] * Avp : 0.f;
        float q2  = Avp * Avp;
        pf();
#pragma unroll
        for (int off = 32; off; off >>= 1) {
            q1 += __shfl_down(q1, off, 64);
            q2 += __shfl_down(q2, off, 64);
        }
        if (lane == 0) { red1[wid] = q1; red2[wid] = q2; }
        __syncthreads();
        float ev   = (red1[0] + red1[1]) + (red1[2] + red1[3]);
        float nrm2 = (red2[0] + red2[1]) + (red2[2] + red2[3]);
        __syncthreads();

        // ---- power iteration (same math/criterion as reference) ----
        for (int it = 0; it < MAXIT; ++it) {
            const float inv = 1.0f / sqrtf(nrm2);
            if (tid < NN) v[tid] = Avp * inv;          // v_new
            pf();
            __syncthreads();                            // v visible
            Avp = (tid < NN) ? matvec_row(Ar4, v4, q0) : 0.f;
            q1  = (tid < NN) ? v[tid] * Avp : 0.f;
            q2  = Avp * Avp;
            pf();
#pragma unroll
            for (int off = 32; off; off >>= 1) {
                q1 += __shfl_down(q1, off, 64);
                q2 += __shfl_down(q2, off, 64);
            }
            if (lane == 0) { red1[wid] = q1; red2[wid] = q2; }
            __syncthreads();
            const float ev_new   = (red1[0] + red1[1]) + (red1[2] + red1[3]);
            const float nrm2_new = (red2[0] + red2[1]) + (red2[2] + red2[3]);
            __syncthreads();
            pf();
            if (fabsf(ev - ev_new) < TOLV) break;       // v holds v_new: matches ref
            ev   = ev_new;
            nrm2 = nrm2_new;
        }

        // ---- drain any remaining prefetch chunks ----
        while (hn && k < NCHUNK) pf();
        __syncthreads();                                // prefetch writes visible

        // ---- deltas: v * (T / v[src]) accumulated into out ----
        const float T     = weights_t[p] * t_paths[p];
        const float scale = T / v[p / NN];
        if (tid < NN) atomicAdd(&out[tid], v[tid] * scale);
        __syncthreads();                                // out reads of v done
        cur ^= 1;
    }
}

extern "C" void kernel_launch(void* const* d_in, const int* in_sizes, int n_in,
                              void* d_out, int out_size, void* d_ws, size_t ws_size,
                              hipStream_t stream) {
    // setup_inputs order: x, r_zeros, r_const, t_paths, weights_t, weights_r
    const float* r_zeros   = (const float*)d_in[1];
    const float* r_const   = (const float*)d_in[2];
    const float* t_paths   = (const float*)d_in[3];
    const float* weights_t = (const float*)d_in[4];
    const float* weights_r = (const float*)d_in[5];
    float* out = (float*)d_out;

    hipMemsetAsync(out, 0, NN * sizeof(float), stream);
    pair_kernel<<<GRID, 256, 0, stream>>>(
        r_zeros, r_const, t_paths, weights_t, weights_r, out);
}

// Round 6
// 444.505 us; speedup vs baseline: 1.1186x; 1.1186x over previous
//
#include <hip/hip_runtime.h>

#define NN 80
#define NP4 1600            // float4 elements per 80x80 tile
#define NPAIR 6400
#define MAXIT 60
#define TOLV 1e-3f

// f32 -> bf16 bits, round-to-nearest-even
__device__ __forceinline__ ushort f2bf(float x) {
    unsigned u = __float_as_uint(x);
    return (ushort)((u + 0x7FFFu + ((u >> 16) & 1u)) >> 16);
}
__device__ __forceinline__ float bflo(unsigned q) { return __uint_as_float(q << 16); }
__device__ __forceinline__ float bfhi(unsigned q) { return __uint_as_float(q & 0xFFFF0000u); }

// dot(A[r,:], v) : A bf16 in LDS (row-major, 80 ushort = 10 x 16B chunks),
// v f32 in LDS. Chunk order staggered by r%10 so the 64 lanes' stride-160B
// row reads spread across bank windows (~3-way instead of 16-way conflict).
__device__ __forceinline__ float rowdot(const ushort* __restrict__ Ab,
                                        const float* __restrict__ vf, int r) {
    const uint4* Ar = (const uint4*)(Ab + r * NN);
    int k = r % 10;
    float s0 = 0.f, s1 = 0.f, s2 = 0.f, s3 = 0.f;
#pragma unroll
    for (int c = 0; c < 10; ++c) {
        const uint4 q = Ar[k];
        const float4* vk = (const float4*)(vf + k * 8);
        const float4 va = vk[0], vb = vk[1];
        s0 = fmaf(bflo(q.x), va.x, s0);  s1 = fmaf(bfhi(q.x), va.y, s1);
        s2 = fmaf(bflo(q.y), va.z, s2);  s3 = fmaf(bfhi(q.y), va.w, s3);
        s0 = fmaf(bflo(q.z), vb.x, s0);  s1 = fmaf(bfhi(q.z), vb.y, s1);
        s2 = fmaf(bflo(q.w), vb.z, s2);  s3 = fmaf(bfhi(q.w), vb.w, s3);
        ++k; if (k == 10) k = 0;
    }
    return (s0 + s1) + (s2 + s3);
}

// One WAVE per pair. No __syncthreads-dependent cross-wave state: 64-thread
// blocks, ~13.2 KB LDS -> 12 resident blocks/CU, all independently active.
template <bool USE_WS>
__global__ __launch_bounds__(64) void pair_kernel(
    const float* __restrict__ r_zeros,
    const float* __restrict__ r_const,
    const float* __restrict__ t_paths,
    const float* __restrict__ weights_t,
    const float* __restrict__ weights_r,
    float* __restrict__ outbuf)   // USE_WS: [NPAIR][NN] deltas ; else [NN] atomic
{
    __shared__ __align__(16) ushort Ab[NN * NN];  // 12.8 KB bf16 A
    __shared__ __align__(16) float  vf[NN];       // 320 B f32 v

    const int lane = threadIdx.x;                 // 0..63
    const int p    = blockIdx.x;
    const long base4 = (long)p * NP4;
    const float4* wr4 = (const float4*)weights_r + base4;
    const float4* rz4 = (const float4*)r_zeros  + base4;
    const float4* rc4 = (const float4*)r_const  + base4;

    // ---- stage A = wr*rz + rc, f32->bf16, 25 float4-triples per lane ----
#pragma unroll 5
    for (int kk = 0; kk < 25; ++kk) {
        const int c = lane + kk * 64;             // 25*64 == 1600 exactly
        const float4 a = wr4[c], b = rz4[c], d = rc4[c];
        ushort4 u;
        u.x = f2bf(fmaf(a.x, b.x, d.x));
        u.y = f2bf(fmaf(a.y, b.y, d.y));
        u.z = f2bf(fmaf(a.z, b.z, d.z));
        u.w = f2bf(fmaf(a.w, b.w, d.w));
        *(ushort4*)&Ab[c * 4] = u;
    }
    const float c0 = 0.11180339887498949f;        // 1/sqrt(80)
    vf[lane] = c0;
    if (lane < 16) vf[64 + lane] = c0;
    __syncthreads();                              // single wave: cheap/elided

    // lane r owns rows r and (r<16) r+64
    float v1 = c0, v2 = (lane < 16) ? c0 : 0.f;
    float a1 = rowdot(Ab, vf, lane);
    float a2 = (lane < 16) ? rowdot(Ab, vf, 64 + lane) : 0.f;
    float e = v1 * a1 + v2 * a2;                  // ev0 = v0 . A v0
    float n = a1 * a1 + a2 * a2;                  // ||A v0||^2
#pragma unroll
    for (int off = 32; off; off >>= 1) {
        e += __shfl_xor(e, off, 64);
        n += __shfl_xor(n, off, 64);
    }
    float ev = e, nrm2 = n;

    // ---- power iteration (identical math/criterion to reference) ----
    for (int it = 0; it < MAXIT; ++it) {
        const float inv = 1.f / sqrtf(nrm2);
        v1 = a1 * inv; v2 = a2 * inv;             // v_new
        vf[lane] = v1;
        if (lane < 16) vf[64 + lane] = v2;
        __syncthreads();
        a1 = rowdot(Ab, vf, lane);
        a2 = (lane < 16) ? rowdot(Ab, vf, 64 + lane) : 0.f;
        e = v1 * a1 + v2 * a2;                    // ev_new
        n = a1 * a1 + a2 * a2;
#pragma unroll
        for (int off = 32; off; off >>= 1) {
            e += __shfl_xor(e, off, 64);
            n += __shfl_xor(n, off, 64);
        }
        if (fabsf(ev - e) < TOLV) break;          // v holds v_new: matches ref
        ev = e; nrm2 = n;
    }

    // ---- deltas = v * (T / v[src]) ----
    const int s_idx = p / NN;
    const float vsrc = (s_idx < 64) ? __shfl(v1, s_idx, 64)
                                    : __shfl(v2, s_idx - 64, 64);
    const float scale = (weights_t[p] * t_paths[p]) / vsrc;
    if (USE_WS) {
        float* od = outbuf + (long)p * NN;
        od[lane] = v1 * scale;
        if (lane < 16) od[64 + lane] = v2 * scale;
    } else {
        atomicAdd(&outbuf[lane], v1 * scale);
        if (lane < 16) atomicAdd(&outbuf[64 + lane], v2 * scale);
    }
}

__global__ __launch_bounds__(256) void reduce_kernel(
    const float* __restrict__ deltas, float* __restrict__ out)
{
    __shared__ float red[4];
    const int j = blockIdx.x;          // one output element per block
    float part = 0.f;
    for (int p = threadIdx.x; p < NPAIR; p += 256)
        part += deltas[(long)p * NN + j];
    const int lane = threadIdx.x & 63;
    const int wid  = threadIdx.x >> 6;
#pragma unroll
    for (int off = 32; off; off >>= 1)
        part += __shfl_down(part, off, 64);
    if (lane == 0) red[wid] = part;
    __syncthreads();
    if (threadIdx.x == 0) out[j] = red[0] + red[1] + red[2] + red[3];
}

extern "C" void kernel_launch(void* const* d_in, const int* in_sizes, int n_in,
                              void* d_out, int out_size, void* d_ws, size_t ws_size,
                              hipStream_t stream) {
    // setup_inputs order: x, r_zeros, r_const, t_paths, weights_t, weights_r
    const float* r_zeros   = (const float*)d_in[1];
    const float* r_const   = (const float*)d_in[2];
    const float* t_paths   = (const float*)d_in[3];
    const float* weights_t = (const float*)d_in[4];
    const float* weights_r = (const float*)d_in[5];
    float* out = (float*)d_out;

    const size_t need = (size_t)NPAIR * NN * sizeof(float);
    if (ws_size >= need) {
        float* deltas = (float*)d_ws;
        pair_kernel<true><<<NPAIR, 64, 0, stream>>>(
            r_zeros, r_const, t_paths, weights_t, weights_r, deltas);
        reduce_kernel<<<NN, 256, 0, stream>>>(deltas, out);
    } else {
        hipMemsetAsync(out, 0, NN * sizeof(float), stream);
        pair_kernel<false><<<NPAIR, 64, 0, stream>>>(
            r_zeros, r_const, t_paths, weights_t, weights_r, out);
    }
}